// Round 8
// baseline (406.915 us; speedup 1.0000x reference)
//
#include <hip/hip_runtime.h>
#include <hip/hip_bf16.h>

#define SEQ   110
#define HALFS 55
#define EMB   102
#define HEAD  192

typedef short bf16x8 __attribute__((ext_vector_type(8)));
typedef float f32x4  __attribute__((ext_vector_type(4)));

#define XS    104               // x/y tile row stride (shorts), 13 granules (odd)
#define XTILE (64 * XS)         // 6656 shorts per half tile
#define MTS   128               // Mt row stride (shorts)
#define MTROWS 112
#define MT_SHORTS (MTROWS * MTS)   // 14336
#define WES   128               // WvT e-stride

__device__ __forceinline__ short f2bf(float f) {
    unsigned u = __float_as_uint(f);
    unsigned r = u + 0x7fffu + ((u >> 16) & 1u);   // RNE
    return (short)(r >> 16);
}
__device__ __forceinline__ unsigned pk2(float a, float b) {
    return ((unsigned)(unsigned short)f2bf(b) << 16) | (unsigned short)f2bf(a);
}

// ws layout: [ Mt : 112x128 bf16 ][ WvT : 192x128 bf16 ]
// Mt[i][j] = scale * sum_h Wq[j][h] * Wk[i][h]   (i = e_out, j = e_in), zero-padded.
// WvT[h][e] = Wv[e][h], zero-padded.
__global__ void prep(const float* __restrict__ Wq, const float* __restrict__ Wk,
                     const float* __restrict__ Wv, short* __restrict__ ws) {
    int flat = blockIdx.x * 256 + threadIdx.x;
    if (flat < MT_SHORTS) {
        int i = flat >> 7, j = flat & 127;
        float v = 0.0f;
        if (i < EMB && j < EMB) {
            const float4* q4 = (const float4*)(Wq + j * HEAD);
            const float4* k4 = (const float4*)(Wk + i * HEAD);
            float s = 0.0f;
            #pragma unroll 4
            for (int h4 = 0; h4 < HEAD / 4; ++h4) {
                float4 a = q4[h4], b = k4[h4];
                s += a.x * b.x + a.y * b.y + a.z * b.z + a.w * b.w;
            }
            v = s * 0.07216878364870322f;   // 1/sqrt(192)
        }
        ws[flat] = f2bf(v);
    } else if (flat < MT_SHORTS + HEAD * WES) {
        int idx = flat - MT_SHORTS;
        int h = idx >> 7, e = idx & 127;
        float v = (e < EMB) ? Wv[e * HEAD + h] : 0.0f;
        ws[flat] = f2bf(v);
    }
}

// 768 persistent blocks -> 3 blocks/CU (LDS-limited: 53.2KB x3 = 159.7KB <= 160KB).
// NOTE: occupancy comes from the GRID, not launch_bounds — R6 was grid-limited at 2/CU.
// Per batch: stage x once, y = x@G once, then both halves run with zero LDS writes /
// zero barriers (all-register P and v redistribution via intra-wave shuffles).
__global__ __launch_bounds__(256, 2)
void attn_head(const float* __restrict__ x, const short* __restrict__ ws,
               float* __restrict__ out, int B) {
    const int tid  = threadIdx.x;
    const int w    = tid >> 6;
    const int lane = tid & 63;
    const int g    = lane >> 4;
    const int r    = lane & 15;

    __shared__ __attribute__((aligned(16))) short ux[2 * XTILE];   // 26624 B
    __shared__ __attribute__((aligned(16))) short uy[2 * XTILE];   // 26624 B

    const short* Mt  = ws;
    const short* WvT = ws + MT_SHORTS;

    // ---- Wv fragments (loop-invariant) ----
    bf16x8 wvf[3][4];
    #pragma unroll
    for (int mi = 0; mi < 3; ++mi) {
        const int hrow = 16 * (w + 4 * mi) + r;
        #pragma unroll
        for (int kk = 0; kk < 4; ++kk)
            wvf[mi][kk] = *(const bf16x8*)(WvT + hrow * WES + 32 * kk + 8 * g);
    }

    // ---- one-time pad zeroing of ux (rows 55..63 both tiles; cols 102/103 rows 0..54) ----
    {
        unsigned long long* z = (unsigned long long*)ux;
        #pragma unroll
        for (int i0 = 0; i0 < 2; ++i0) {
            int ii = tid + i0 * 256;
            if (ii < 468) z[(ii < 234 ? 1430 : 2860) + ii] = 0ull;
        }
        if (tid < 110)
            *(unsigned*)(ux + (tid & 1) * XTILE + (tid >> 1) * XS + 102) = 0u;
    }

    unsigned xv0[11], xv1[11];
    auto loadx = [&](int batch) {
        const float4* xb4 = (const float4*)(x + (size_t)batch * (SEQ * EMB));
        #pragma unroll
        for (int it = 0; it < 11; ++it) {
            int i4 = tid + it * 256;
            if (i4 < 2805) { float4 v = xb4[i4]; xv0[it] = pk2(v.x, v.y); xv1[it] = pk2(v.z, v.w); }
        }
    };
    auto stagex = [&]() {
        #pragma unroll
        for (int it = 0; it < 11; ++it) {
            int i4 = tid + it * 256;
            if (i4 < 2805) {
                int fc  = i4 * 4;
                int row = (int)(((unsigned long long)fc * 41121ull) >> 22);  // /102
                int e   = fc - row * EMB;
                int tile = row >= HALFS;
                int lr   = row - HALFS * tile;
                int ba   = tile * XTILE + lr * XS + e;
                if (e == 100) {
                    int rowb  = row + 1;
                    int tileb = rowb >= HALFS;
                    int lrb   = rowb - HALFS * tileb;
                    *(unsigned*)(ux + ba) = xv0[it];
                    *(unsigned*)(ux + tileb * XTILE + lrb * XS) = xv1[it];
                } else {
                    uint2 t2; t2.x = xv0[it]; t2.y = xv1[it];
                    *(uint2*)(ux + ba) = t2;
                }
            }
        }
    };

    loadx(blockIdx.x);
    const int stride = (int)gridDim.x;

    #pragma unroll 1
    for (int p = blockIdx.x; p < B; p += stride) {
        stagex();
        __syncthreads();                 // bar A: x staged (+ pads, first iter)

        // ---- y-GEMM: y = x @ G, both halves, once per batch ----
        {
            bf16x8 am[2][4];
            bf16x8 zz = {};
            #pragma unroll
            for (int mi2 = 0; mi2 < 2; ++mi2) {
                const int mt = w + 4 * mi2;
                #pragma unroll
                for (int kk = 0; kk < 4; ++kk)
                    am[mi2][kk] = (mt < 7) ? *(const bf16x8*)(Mt + (16 * mt + r) * MTS + 32 * kk + 8 * g) : zz;
            }
            #pragma unroll
            for (int stl = 0; stl < 8; ++stl) {
                const short* xb = ux + (stl >> 2) * XTILE + (16 * (stl & 3) + r) * XS;
                bf16x8 bx[4];
                #pragma unroll
                for (int kk = 0; kk < 3; ++kk) bx[kk] = *(const bf16x8*)(xb + 32 * kk + 8 * g);
                bx[3] = zz;
                if (g == 0) bx[3] = *(const bf16x8*)(xb + 96);
                #pragma unroll
                for (int mi2 = 0; mi2 < 2; ++mi2) {
                    const int mt = w + 4 * mi2;
                    if (mt < 7) {
                        f32x4 acc = {0.f, 0.f, 0.f, 0.f};
                        #pragma unroll
                        for (int kk = 0; kk < 4; ++kk)
                            acc = __builtin_amdgcn_mfma_f32_16x16x32_bf16(am[mi2][kk], bx[kk], acc, 0, 0, 0);
                        if (mt < 6 || g < 2) {
                            uint2 t2; t2.x = pk2(acc[0], acc[1]); t2.y = pk2(acc[2], acc[3]);
                            *(uint2*)(uy + (stl >> 2) * XTILE + (16 * (stl & 3) + r) * XS + 16 * mt + 4 * g) = t2;
                        }
                    }
                }
            }
        }
        __syncthreads();                 // bar B: y visible

        if (p + stride < B) loadx(p + stride);   // HBM latency spans both halves

        #pragma unroll
        for (int half = 0; half < 2; ++half) {
            const short* xo = ux + (half ^ 1) * XTILE;   // keys/values rows
            const short* yo = uy + half * XTILE;         // own-half y rows

            // ---- hoist x_oth A-frags (shared by scores AND v-GEMM) ----
            bf16x8 ax[4][4];
            bf16x8 zz = {};
            #pragma unroll
            for (int mt = 0; mt < 4; ++mt) {
                const short* xb = xo + (16 * mt + r) * XS;
                #pragma unroll
                for (int kk = 0; kk < 3; ++kk) ax[mt][kk] = *(const bf16x8*)(xb + 32 * kk + 8 * g);
                ax[mt][3] = zz;
                if (g == 0) ax[mt][3] = *(const bf16x8*)(xb + 96);
            }

            const int src0 = ((g & 1) << 5) + r;
            const int src1 = src0 + 16;
            const bool hi  = (g >> 1) != 0;

            // ---- scoresT + softmax + P-exchange, per s-tile c (all waves, all c) ----
            bf16x8 bpA[4], bpB[4];
            #pragma unroll
            for (int c = 0; c < 4; ++c) {
                const short* yb = yo + (16 * c + r) * XS;
                bf16x8 by[4];
                #pragma unroll
                for (int kk = 0; kk < 3; ++kk) by[kk] = *(const bf16x8*)(yb + 32 * kk + 8 * g);
                by[3] = zz;
                if (g == 0) by[3] = *(const bf16x8*)(yb + 96);

                float sc[4][4];
                #pragma unroll
                for (int mt = 0; mt < 4; ++mt) {
                    f32x4 acc = {0.f, 0.f, 0.f, 0.f};
                    #pragma unroll
                    for (int kk = 0; kk < 4; ++kk)
                        acc = __builtin_amdgcn_mfma_f32_16x16x32_bf16(ax[mt][kk], by[kk], acc, 0, 0, 0);
                    #pragma unroll
                    for (int j = 0; j < 4; ++j) sc[mt][j] = acc[j];
                }
                #pragma unroll
                for (int j = 0; j < 4; ++j)
                    if (48 + 4 * g + j >= HALFS) sc[3][j] = -1e30f;

                float mx = -1e30f;
                #pragma unroll
                for (int mt = 0; mt < 4; ++mt) {
                    #pragma unroll
                    for (int j = 0; j < 4; ++j) mx = fmaxf(mx, sc[mt][j]);
                }
                mx = fmaxf(mx, __shfl_xor(mx, 16));
                mx = fmaxf(mx, __shfl_xor(mx, 32));
                float pr[4][4];
                float sum = 0.f;
                #pragma unroll
                for (int mt = 0; mt < 4; ++mt) {
                    #pragma unroll
                    for (int j = 0; j < 4; ++j) { pr[mt][j] = __expf(sc[mt][j] - mx); sum += pr[mt][j]; }
                }
                sum += __shfl_xor(sum, 16);
                sum += __shfl_xor(sum, 32);
                float rs = 1.0f / sum;

                unsigned pu[4][2];
                #pragma unroll
                for (int mt = 0; mt < 4; ++mt) {
                    pu[mt][0] = pk2(pr[mt][0] * rs, pr[mt][1] * rs);
                    pu[mt][1] = pk2(pr[mt][2] * rs, pr[mt][3] * rs);
                }
                // P exchange (verified R4-R6): bpA = P[s=16c+r][t=8g..8g+7], bpB = +32
                unsigned A00 = (unsigned)__shfl((int)pu[0][0], src0), A01 = (unsigned)__shfl((int)pu[0][1], src0);
                unsigned A02 = (unsigned)__shfl((int)pu[0][0], src1), A03 = (unsigned)__shfl((int)pu[0][1], src1);
                unsigned B00 = (unsigned)__shfl((int)pu[1][0], src0), B01 = (unsigned)__shfl((int)pu[1][1], src0);
                unsigned B02 = (unsigned)__shfl((int)pu[1][0], src1), B03 = (unsigned)__shfl((int)pu[1][1], src1);
                unsigned C00 = (unsigned)__shfl((int)pu[2][0], src0), C01 = (unsigned)__shfl((int)pu[2][1], src0);
                unsigned C02 = (unsigned)__shfl((int)pu[2][0], src1), C03 = (unsigned)__shfl((int)pu[2][1], src1);
                unsigned D00 = (unsigned)__shfl((int)pu[3][0], src0), D01 = (unsigned)__shfl((int)pu[3][1], src0);
                unsigned D02 = (unsigned)__shfl((int)pu[3][0], src1), D03 = (unsigned)__shfl((int)pu[3][1], src1);
                uint4 q0, q1;
                q0.x = hi ? B00 : A00; q0.y = hi ? B01 : A01; q0.z = hi ? B02 : A02; q0.w = hi ? B03 : A03;
                q1.x = hi ? D00 : C00; q1.y = hi ? D01 : C01; q1.z = hi ? D02 : C02; q1.w = hi ? D03 : C03;
                __builtin_memcpy(&bpA[c], &q0, 16);
                __builtin_memcpy(&bpB[c], &q1, 16);
            }

            // ---- v-GEMM (reuses ax; no LDS access at all) ----
            unsigned vpk[4][3][2];
            #pragma unroll
            for (int st = 0; st < 4; ++st) {
                #pragma unroll
                for (int mi = 0; mi < 3; ++mi) {
                    f32x4 acc = {0.f, 0.f, 0.f, 0.f};
                    #pragma unroll
                    for (int kk = 0; kk < 4; ++kk)
                        acc = __builtin_amdgcn_mfma_f32_16x16x32_bf16(ax[st][kk], wvf[mi][kk], acc, 0, 0, 0);
                    vpk[st][mi][0] = pk2(acc[0], acc[1]);
                    vpk[st][mi][1] = pk2(acc[2], acc[3]);
                }
            }

            // ---- v-exchange (intra-wave) + PV + stores ----
            const size_t obase = (size_t)p * (SEQ * HEAD) + (size_t)(half * HALFS) * HEAD;
            #pragma unroll
            for (int mi = 0; mi < 3; ++mi) {
                unsigned e00 = (unsigned)__shfl((int)vpk[0][mi][0], src0), e01 = (unsigned)__shfl((int)vpk[0][mi][1], src0);
                unsigned e02 = (unsigned)__shfl((int)vpk[0][mi][0], src1), e03 = (unsigned)__shfl((int)vpk[0][mi][1], src1);
                unsigned f00 = (unsigned)__shfl((int)vpk[1][mi][0], src0), f01 = (unsigned)__shfl((int)vpk[1][mi][1], src0);
                unsigned f02 = (unsigned)__shfl((int)vpk[1][mi][0], src1), f03 = (unsigned)__shfl((int)vpk[1][mi][1], src1);
                uint4 u0;
                u0.x = hi ? f00 : e00; u0.y = hi ? f01 : e01; u0.z = hi ? f02 : e02; u0.w = hi ? f03 : e03;
                unsigned e10 = (unsigned)__shfl((int)vpk[2][mi][0], src0), e11 = (unsigned)__shfl((int)vpk[2][mi][1], src0);
                unsigned e12 = (unsigned)__shfl((int)vpk[2][mi][0], src1), e13 = (unsigned)__shfl((int)vpk[2][mi][1], src1);
                unsigned f10 = (unsigned)__shfl((int)vpk[3][mi][0], src0), f11 = (unsigned)__shfl((int)vpk[3][mi][1], src0);
                unsigned f12 = (unsigned)__shfl((int)vpk[3][mi][0], src1), f13 = (unsigned)__shfl((int)vpk[3][mi][1], src1);
                uint4 u1;
                u1.x = hi ? f10 : e10; u1.y = hi ? f11 : e11; u1.z = hi ? f12 : e12; u1.w = hi ? f13 : e13;
                bf16x8 va0, va1;
                __builtin_memcpy(&va0, &u0, 16);
                __builtin_memcpy(&va1, &u1, 16);

                #pragma unroll
                for (int c = 0; c < 4; ++c) {
                    f32x4 acc = {0.f, 0.f, 0.f, 0.f};
                    acc = __builtin_amdgcn_mfma_f32_16x16x32_bf16(va0, bpA[c], acc, 0, 0, 0);
                    acc = __builtin_amdgcn_mfma_f32_16x16x32_bf16(va1, bpB[c], acc, 0, 0, 0);
                    const int srow = 16 * c + r;
                    if (srow < HALFS) {
                        float4 st4; st4.x = acc[0]; st4.y = acc[1]; st4.z = acc[2]; st4.w = acc[3];
                        *(float4*)(out + obase + (size_t)srow * HEAD + 16 * (w + 4 * mi) + 4 * g) = st4;
                    }
                }
            }
        }
        __syncthreads();                 // bar C: all ux/uy reads done before restage
    }
}

extern "C" void kernel_launch(void* const* d_in, const int* in_sizes, int n_in,
                              void* d_out, int out_size, void* d_ws, size_t ws_size,
                              hipStream_t stream) {
    const float* x  = (const float*)d_in[0];
    const float* Wq = (const float*)d_in[1];
    const float* Wk = (const float*)d_in[2];
    const float* Wv = (const float*)d_in[3];
    short* ws = (short*)d_ws;                       // needs (14336+24576)*2 = 77824 B
    int B = in_sizes[0] / (SEQ * EMB);              // 8192
    int prep_elems = MT_SHORTS + HEAD * WES;
    prep<<<(prep_elems + 255) / 256, 256, 0, stream>>>(Wq, Wk, Wv, ws);
    attn_head<<<768, 256, 0, stream>>>(x, ws, (float*)d_out, B);
}

// Round 9
// 390.827 us; speedup vs baseline: 1.0412x; 1.0412x over previous
//
#include <hip/hip_runtime.h>
#include <hip/hip_bf16.h>

#define SEQ   110
#define HALFS 55
#define EMB   102
#define HEAD  192

typedef short bf16x8 __attribute__((ext_vector_type(8)));
typedef float f32x4  __attribute__((ext_vector_type(4)));

#define XS    104               // tile row stride (shorts), 13 granules (odd)
#define XTILE (64 * XS)         // 6656 shorts per tile
#define MTS   128               // Mt row stride (shorts)
#define MTROWS 112
#define MT_SHORTS (MTROWS * MTS)   // 14336
#define WES   128               // WvT e-stride

__device__ __forceinline__ short f2bf(float f) {
    unsigned u = __float_as_uint(f);
    unsigned r = u + 0x7fffu + ((u >> 16) & 1u);   // RNE
    return (short)(r >> 16);
}
__device__ __forceinline__ unsigned pk2(float a, float b) {
    return ((unsigned)(unsigned short)f2bf(b) << 16) | (unsigned short)f2bf(a);
}

// ws layout: [ Mt : 112x128 bf16 ][ WvT : 192x128 bf16 ]
// Mt[i][j] = scale * sum_h Wq[j][h] * Wk[i][h]; WvT[h][e] = Wv[e][h]; zero-padded.
__global__ void prep(const float* __restrict__ Wq, const float* __restrict__ Wk,
                     const float* __restrict__ Wv, short* __restrict__ ws) {
    int flat = blockIdx.x * 256 + threadIdx.x;
    if (flat < MT_SHORTS) {
        int i = flat >> 7, j = flat & 127;
        float v = 0.0f;
        if (i < EMB && j < EMB) {
            const float4* q4 = (const float4*)(Wq + j * HEAD);
            const float4* k4 = (const float4*)(Wk + i * HEAD);
            float s = 0.0f;
            #pragma unroll 4
            for (int h4 = 0; h4 < HEAD / 4; ++h4) {
                float4 a = q4[h4], b = k4[h4];
                s += a.x * b.x + a.y * b.y + a.z * b.z + a.w * b.w;
            }
            v = s * 0.07216878364870322f;   // 1/sqrt(192)
        }
        ws[flat] = f2bf(v);
    } else if (flat < MT_SHORTS + HEAD * WES) {
        int idx = flat - MT_SHORTS;
        int h = idx >> 7, e = idx & 127;
        float v = (e < EMB) ? Wv[e * HEAD + h] : 0.0f;
        ws[flat] = f2bf(v);
    }
}

// 768 persistent blocks, LDS 39.9KB -> >=3 blocks/CU guaranteed.
// 3-slot overlay: slotA=x0, slotB=x1 then y1 (y1's B-frags come from ax REGISTERS,
// written during half-0 compute), slotC=y0. y=x@G is row-wise so y_h = x_h@G.
__global__ __launch_bounds__(256, 2)
void attn_head(const float* __restrict__ x, const short* __restrict__ ws,
               float* __restrict__ out, int B) {
    const int tid  = threadIdx.x;
    const int w    = tid >> 6;
    const int lane = tid & 63;
    const int g    = lane >> 4;
    const int r    = lane & 15;

    __shared__ __attribute__((aligned(16))) short u[3 * XTILE];   // 39936 B
    short* slotA = u;                 // x half0
    short* slotB = u + XTILE;         // x half1 -> y half1
    short* slotC = u + 2 * XTILE;     // y half0

    const short* Mt  = ws;
    const short* WvT = ws + MT_SHORTS;

    // ---- Wv fragments (loop-invariant, 48 VGPR) ----
    bf16x8 wvf[3][4];
    #pragma unroll
    for (int mi = 0; mi < 3; ++mi) {
        const int hrow = 16 * (w + 4 * mi) + r;
        #pragma unroll
        for (int kk = 0; kk < 4; ++kk)
            wvf[mi][kk] = *(const bf16x8*)(WvT + hrow * WES + 32 * kk + 8 * g);
    }

    // ---- one-time pad zeroing of slotA/slotB (rows 55..63; cols 102/103 rows 0..54) ----
    {
        unsigned long long* z = (unsigned long long*)u;
        #pragma unroll
        for (int i0 = 0; i0 < 2; ++i0) {
            int ii = tid + i0 * 256;
            if (ii < 468) z[(ii < 234 ? 1430 : 2860) + ii] = 0ull;
        }
        if (tid < 110)
            *(unsigned*)(u + (tid & 1) * XTILE + (tid >> 1) * XS + 102) = 0u;
    }

    unsigned xv0[11], xv1[11];
    auto loadx = [&](int batch) {
        const float4* xb4 = (const float4*)(x + (size_t)batch * (SEQ * EMB));
        #pragma unroll
        for (int it = 0; it < 11; ++it) {
            int i4 = tid + it * 256;
            if (i4 < 2805) { float4 v = xb4[i4]; xv0[it] = pk2(v.x, v.y); xv1[it] = pk2(v.z, v.w); }
        }
    };
    auto stagex = [&]() {
        #pragma unroll
        for (int it = 0; it < 11; ++it) {
            int i4 = tid + it * 256;
            if (i4 < 2805) {
                int fc  = i4 * 4;
                int row = (int)(((unsigned long long)fc * 41121ull) >> 22);  // /102
                int e   = fc - row * EMB;
                int tile = row >= HALFS;
                int lr   = row - HALFS * tile;
                int ba   = tile * XTILE + lr * XS + e;
                if (e == 100) {
                    int rowb  = row + 1;
                    int tileb = rowb >= HALFS;
                    int lrb   = rowb - HALFS * tileb;
                    *(unsigned*)(u + ba) = xv0[it];
                    *(unsigned*)(u + tileb * XTILE + lrb * XS) = xv1[it];
                } else {
                    uint2 t2; t2.x = xv0[it]; t2.y = xv1[it];
                    *(uint2*)(u + ba) = t2;
                }
            }
        }
    };

    loadx(blockIdx.x);
    const int stride = (int)gridDim.x;

    bf16x8 ax[4][4];   // current keys-half x fragments (shared: scores A, v-GEMM A, y1 B)

    #pragma unroll 1
    for (int p = blockIdx.x; p < B; p += stride) {
        stagex();
        __syncthreads();                 // bar1: x staged

        // ---- G A-frags loaded per batch (live range dies before register-peak phases) ----
        bf16x8 am[2][4];
        bf16x8 zz = {};
        #pragma unroll
        for (int mi2 = 0; mi2 < 2; ++mi2) {
            const int mt = w + 4 * mi2;
            #pragma unroll
            for (int kk = 0; kk < 4; ++kk)
                am[mi2][kk] = (mt < 7) ? *(const bf16x8*)(Mt + (16 * mt + r) * MTS + 32 * kk + 8 * g) : zz;
        }

        // ---- y0-GEMM: y0 = x0 @ G  (B-frags from slotA) -> slotC ----
        #pragma unroll
        for (int stl = 0; stl < 4; ++stl) {
            const short* xb = slotA + (16 * stl + r) * XS;
            bf16x8 bx[4];
            #pragma unroll
            for (int kk = 0; kk < 3; ++kk) bx[kk] = *(const bf16x8*)(xb + 32 * kk + 8 * g);
            bx[3] = zz;
            if (g == 0) bx[3] = *(const bf16x8*)(xb + 96);
            #pragma unroll
            for (int mi2 = 0; mi2 < 2; ++mi2) {
                const int mt = w + 4 * mi2;
                if (mt < 7) {
                    f32x4 acc = {0.f, 0.f, 0.f, 0.f};
                    #pragma unroll
                    for (int kk = 0; kk < 4; ++kk)
                        acc = __builtin_amdgcn_mfma_f32_16x16x32_bf16(am[mi2][kk], bx[kk], acc, 0, 0, 0);
                    if (mt < 6 || g < 2) {
                        uint2 t2; t2.x = pk2(acc[0], acc[1]); t2.y = pk2(acc[2], acc[3]);
                        *(uint2*)(slotC + (16 * stl + r) * XS + 16 * mt + 4 * g) = t2;
                    }
                }
            }
        }
        __syncthreads();                 // bar2: y0 visible

        // ---- hoist ax = x1 fragments (slotB) ----
        #pragma unroll
        for (int mt = 0; mt < 4; ++mt) {
            const short* xb = slotB + (16 * mt + r) * XS;
            #pragma unroll
            for (int kk = 0; kk < 3; ++kk) ax[mt][kk] = *(const bf16x8*)(xb + 32 * kk + 8 * g);
            ax[mt][3] = zz;
            if (g == 0) ax[mt][3] = *(const bf16x8*)(xb + 96);
        }
        __syncthreads();                 // bar2b: all waves' x1 hoists done -> slotB writable

        // ---- y1-GEMM: y1 = x1 @ G, B-frags = ax REGISTERS (zero LDS reads) -> slotB ----
        #pragma unroll
        for (int stl = 0; stl < 4; ++stl) {
            #pragma unroll
            for (int mi2 = 0; mi2 < 2; ++mi2) {
                const int mt = w + 4 * mi2;
                if (mt < 7) {
                    f32x4 acc = {0.f, 0.f, 0.f, 0.f};
                    #pragma unroll
                    for (int kk = 0; kk < 4; ++kk)
                        acc = __builtin_amdgcn_mfma_f32_16x16x32_bf16(am[mi2][kk], ax[stl][kk], acc, 0, 0, 0);
                    if (mt < 6 || g < 2) {
                        uint2 t2; t2.x = pk2(acc[0], acc[1]); t2.y = pk2(acc[2], acc[3]);
                        *(uint2*)(slotB + (16 * stl + r) * XS + 16 * mt + 4 * g) = t2;
                    }
                }
            }
        }

        if (p + stride < B) loadx(p + stride);   // HBM latency spans the halves

        const int src0 = ((g & 1) << 5) + r;
        const int src1 = src0 + 16;
        const bool hi  = (g >> 1) != 0;

        // ---- per-half compute (identical math to R6; ax pre-hoisted; yo passed in) ----
        auto do_half = [&](int half, const short* yo) {
            // scoresT + softmax + P-exchange, per s-tile c
            bf16x8 bpA[4], bpB[4];
            #pragma unroll
            for (int c = 0; c < 4; ++c) {
                const short* yb = yo + (16 * c + r) * XS;
                bf16x8 by[4];
                #pragma unroll
                for (int kk = 0; kk < 3; ++kk) by[kk] = *(const bf16x8*)(yb + 32 * kk + 8 * g);
                by[3] = zz;
                if (g == 0) by[3] = *(const bf16x8*)(yb + 96);

                float sc[4][4];
                #pragma unroll
                for (int mt = 0; mt < 4; ++mt) {
                    f32x4 acc = {0.f, 0.f, 0.f, 0.f};
                    #pragma unroll
                    for (int kk = 0; kk < 4; ++kk)
                        acc = __builtin_amdgcn_mfma_f32_16x16x32_bf16(ax[mt][kk], by[kk], acc, 0, 0, 0);
                    #pragma unroll
                    for (int j = 0; j < 4; ++j) sc[mt][j] = acc[j];
                }
                #pragma unroll
                for (int j = 0; j < 4; ++j)
                    if (48 + 4 * g + j >= HALFS) sc[3][j] = -1e30f;

                float mx = -1e30f;
                #pragma unroll
                for (int mt = 0; mt < 4; ++mt) {
                    #pragma unroll
                    for (int j = 0; j < 4; ++j) mx = fmaxf(mx, sc[mt][j]);
                }
                mx = fmaxf(mx, __shfl_xor(mx, 16));
                mx = fmaxf(mx, __shfl_xor(mx, 32));
                float pr[4][4];
                float sum = 0.f;
                #pragma unroll
                for (int mt = 0; mt < 4; ++mt) {
                    #pragma unroll
                    for (int j = 0; j < 4; ++j) { pr[mt][j] = __expf(sc[mt][j] - mx); sum += pr[mt][j]; }
                }
                sum += __shfl_xor(sum, 16);
                sum += __shfl_xor(sum, 32);
                float rs = 1.0f / sum;

                unsigned pu[4][2];
                #pragma unroll
                for (int mt = 0; mt < 4; ++mt) {
                    pu[mt][0] = pk2(pr[mt][0] * rs, pr[mt][1] * rs);
                    pu[mt][1] = pk2(pr[mt][2] * rs, pr[mt][3] * rs);
                }
                unsigned A00 = (unsigned)__shfl((int)pu[0][0], src0), A01 = (unsigned)__shfl((int)pu[0][1], src0);
                unsigned A02 = (unsigned)__shfl((int)pu[0][0], src1), A03 = (unsigned)__shfl((int)pu[0][1], src1);
                unsigned B00 = (unsigned)__shfl((int)pu[1][0], src0), B01 = (unsigned)__shfl((int)pu[1][1], src0);
                unsigned B02 = (unsigned)__shfl((int)pu[1][0], src1), B03 = (unsigned)__shfl((int)pu[1][1], src1);
                unsigned C00 = (unsigned)__shfl((int)pu[2][0], src0), C01 = (unsigned)__shfl((int)pu[2][1], src0);
                unsigned C02 = (unsigned)__shfl((int)pu[2][0], src1), C03 = (unsigned)__shfl((int)pu[2][1], src1);
                unsigned D00 = (unsigned)__shfl((int)pu[3][0], src0), D01 = (unsigned)__shfl((int)pu[3][1], src0);
                unsigned D02 = (unsigned)__shfl((int)pu[3][0], src1), D03 = (unsigned)__shfl((int)pu[3][1], src1);
                uint4 q0, q1;
                q0.x = hi ? B00 : A00; q0.y = hi ? B01 : A01; q0.z = hi ? B02 : A02; q0.w = hi ? B03 : A03;
                q1.x = hi ? D00 : C00; q1.y = hi ? D01 : C01; q1.z = hi ? D02 : C02; q1.w = hi ? D03 : C03;
                __builtin_memcpy(&bpA[c], &q0, 16);
                __builtin_memcpy(&bpB[c], &q1, 16);
            }

            // v-GEMM (A = ax regs, B = wvf regs; no LDS)
            unsigned vpk[4][3][2];
            #pragma unroll
            for (int st = 0; st < 4; ++st) {
                #pragma unroll
                for (int mi = 0; mi < 3; ++mi) {
                    f32x4 acc = {0.f, 0.f, 0.f, 0.f};
                    #pragma unroll
                    for (int kk = 0; kk < 4; ++kk)
                        acc = __builtin_amdgcn_mfma_f32_16x16x32_bf16(ax[st][kk], wvf[mi][kk], acc, 0, 0, 0);
                    vpk[st][mi][0] = pk2(acc[0], acc[1]);
                    vpk[st][mi][1] = pk2(acc[2], acc[3]);
                }
            }

            // v-exchange + PV + stores
            const size_t obase = (size_t)p * (SEQ * HEAD) + (size_t)(half * HALFS) * HEAD;
            #pragma unroll
            for (int mi = 0; mi < 3; ++mi) {
                unsigned e00 = (unsigned)__shfl((int)vpk[0][mi][0], src0), e01 = (unsigned)__shfl((int)vpk[0][mi][1], src0);
                unsigned e02 = (unsigned)__shfl((int)vpk[0][mi][0], src1), e03 = (unsigned)__shfl((int)vpk[0][mi][1], src1);
                unsigned f00 = (unsigned)__shfl((int)vpk[1][mi][0], src0), f01 = (unsigned)__shfl((int)vpk[1][mi][1], src0);
                unsigned f02 = (unsigned)__shfl((int)vpk[1][mi][0], src1), f03 = (unsigned)__shfl((int)vpk[1][mi][1], src1);
                uint4 u0;
                u0.x = hi ? f00 : e00; u0.y = hi ? f01 : e01; u0.z = hi ? f02 : e02; u0.w = hi ? f03 : e03;
                unsigned e10 = (unsigned)__shfl((int)vpk[2][mi][0], src0), e11 = (unsigned)__shfl((int)vpk[2][mi][1], src0);
                unsigned e12 = (unsigned)__shfl((int)vpk[2][mi][0], src1), e13 = (unsigned)__shfl((int)vpk[2][mi][1], src1);
                unsigned f10 = (unsigned)__shfl((int)vpk[3][mi][0], src0), f11 = (unsigned)__shfl((int)vpk[3][mi][1], src0);
                unsigned f12 = (unsigned)__shfl((int)vpk[3][mi][0], src1), f13 = (unsigned)__shfl((int)vpk[3][mi][1], src1);
                uint4 u1;
                u1.x = hi ? f10 : e10; u1.y = hi ? f11 : e11; u1.z = hi ? f12 : e12; u1.w = hi ? f13 : e13;
                bf16x8 va0, va1;
                __builtin_memcpy(&va0, &u0, 16);
                __builtin_memcpy(&va1, &u1, 16);

                #pragma unroll
                for (int c = 0; c < 4; ++c) {
                    f32x4 acc = {0.f, 0.f, 0.f, 0.f};
                    acc = __builtin_amdgcn_mfma_f32_16x16x32_bf16(va0, bpA[c], acc, 0, 0, 0);
                    acc = __builtin_amdgcn_mfma_f32_16x16x32_bf16(va1, bpB[c], acc, 0, 0, 0);
                    const int srow = 16 * c + r;
                    if (srow < HALFS) {
                        float4 st4; st4.x = acc[0]; st4.y = acc[1]; st4.z = acc[2]; st4.w = acc[3];
                        *(float4*)(out + obase + (size_t)srow * HEAD + 16 * (w + 4 * mi) + 4 * g) = st4;
                    }
                }
            }
        };

        // half 0: keys/values = x1 (ax), scores vs y0 (slotC); y1 writes to slotB overlap
        do_half(0, slotC);
        __syncthreads();                 // bar3: y1 visible; slotC reads done

        // half 1: keys/values = x0 -> rehoist ax from slotA; scores vs y1 (slotB)
        #pragma unroll
        for (int mt = 0; mt < 4; ++mt) {
            const short* xb = slotA + (16 * mt + r) * XS;
            #pragma unroll
            for (int kk = 0; kk < 3; ++kk) ax[mt][kk] = *(const bf16x8*)(xb + 32 * kk + 8 * g);
            ax[mt][3] = zz;
            if (g == 0) ax[mt][3] = *(const bf16x8*)(xb + 96);
        }
        do_half(1, slotB);
        __syncthreads();                 // bar4: slotA/slotB reads done before next stage
    }
}

extern "C" void kernel_launch(void* const* d_in, const int* in_sizes, int n_in,
                              void* d_out, int out_size, void* d_ws, size_t ws_size,
                              hipStream_t stream) {
    const float* x  = (const float*)d_in[0];
    const float* Wq = (const float*)d_in[1];
    const float* Wk = (const float*)d_in[2];
    const float* Wv = (const float*)d_in[3];
    short* ws = (short*)d_ws;                       // needs (14336+24576)*2 = 77824 B
    int B = in_sizes[0] / (SEQ * EMB);              // 8192
    int prep_elems = MT_SHORTS + HEAD * WES;
    prep<<<(prep_elems + 255) / 256, 256, 0, stream>>>(Wq, Wk, Wv, ws);
    attn_head<<<768, 256, 0, stream>>>(x, ws, (float*)d_out, B);
}

// Round 10
// 353.994 us; speedup vs baseline: 1.1495x; 1.1040x over previous
//
#include <hip/hip_runtime.h>
#include <hip/hip_bf16.h>

#define SEQ   110
#define HALFS 55
#define EMB   102
#define HEAD  192

typedef short bf16x8 __attribute__((ext_vector_type(8)));
typedef float f32x4  __attribute__((ext_vector_type(4)));

#define XS    104               // tile row stride (shorts), 13 granules (odd)
#define XTILE (64 * XS)         // 6656 shorts per tile
#define MTS   128               // Mt row stride (shorts)
#define MTROWS 112
#define MT_SHORTS (MTROWS * MTS)   // 14336
#define WES   128               // WvT e-stride

__device__ __forceinline__ short f2bf(float f) {
    unsigned u = __float_as_uint(f);
    unsigned r = u + 0x7fffu + ((u >> 16) & 1u);   // RNE
    return (short)(r >> 16);
}
__device__ __forceinline__ unsigned pk2(float a, float b) {
    return ((unsigned)(unsigned short)f2bf(b) << 16) | (unsigned short)f2bf(a);
}

// ws layout: [ Mt : 112x128 bf16 ][ WvT : 192x128 bf16 ]
// Mt[i][j] = scale * sum_h Wq[j][h] * Wk[i][h]; WvT[h][e] = Wv[e][h]; zero-padded.
__global__ void prep(const float* __restrict__ Wq, const float* __restrict__ Wk,
                     const float* __restrict__ Wv, short* __restrict__ ws) {
    int flat = blockIdx.x * 256 + threadIdx.x;
    if (flat < MT_SHORTS) {
        int i = flat >> 7, j = flat & 127;
        float v = 0.0f;
        if (i < EMB && j < EMB) {
            const float4* q4 = (const float4*)(Wq + j * HEAD);
            const float4* k4 = (const float4*)(Wk + i * HEAD);
            float s = 0.0f;
            #pragma unroll 4
            for (int h4 = 0; h4 < HEAD / 4; ++h4) {
                float4 a = q4[h4], b = k4[h4];
                s += a.x * b.x + a.y * b.y + a.z * b.z + a.w * b.w;
            }
            v = s * 0.07216878364870322f;   // 1/sqrt(192)
        }
        ws[flat] = f2bf(v);
    } else if (flat < MT_SHORTS + HEAD * WES) {
        int idx = flat - MT_SHORTS;
        int h = idx >> 7, e = idx & 127;
        float v = (e < EMB) ? Wv[e * HEAD + h] : 0.0f;
        ws[flat] = f2bf(v);
    }
}

// 512 persistent blocks (balanced: 16 batches each), LDS 39.9KB.
// CODE-SIZE probe: half-loop and c-loop ROLLED (#pragma unroll 1) so the fat
// score/softmax/exchange/PV body is emitted ONCE (was 8x) — I$-thrash hypothesis.
// Math, LDS layout, barrier graph identical to the passing R6/R9 lineage.
__global__ __launch_bounds__(256, 2)
void attn_head(const float* __restrict__ x, const short* __restrict__ ws,
               float* __restrict__ out, int B) {
    const int tid  = threadIdx.x;
    const int w    = tid >> 6;
    const int lane = tid & 63;
    const int g    = lane >> 4;
    const int r    = lane & 15;

    __shared__ __attribute__((aligned(16))) short u[3 * XTILE];   // 39936 B
    short* slotA = u;                 // x half0
    short* slotB = u + XTILE;         // x half1 -> y half1
    short* slotC = u + 2 * XTILE;     // y half0

    const short* Mt  = ws;
    const short* WvT = ws + MT_SHORTS;

    bf16x8 wvf[3][4];
    #pragma unroll
    for (int mi = 0; mi < 3; ++mi) {
        const int hrow = 16 * (w + 4 * mi) + r;
        #pragma unroll
        for (int kk = 0; kk < 4; ++kk)
            wvf[mi][kk] = *(const bf16x8*)(WvT + hrow * WES + 32 * kk + 8 * g);
    }

    // one-time pad zeroing of slotA/slotB
    {
        unsigned long long* z = (unsigned long long*)u;
        #pragma unroll
        for (int i0 = 0; i0 < 2; ++i0) {
            int ii = tid + i0 * 256;
            if (ii < 468) z[(ii < 234 ? 1430 : 2860) + ii] = 0ull;
        }
        if (tid < 110)
            *(unsigned*)(u + (tid & 1) * XTILE + (tid >> 1) * XS + 102) = 0u;
    }

    unsigned xv0[11], xv1[11];
    auto loadx = [&](int batch) {
        const float4* xb4 = (const float4*)(x + (size_t)batch * (SEQ * EMB));
        #pragma unroll
        for (int it = 0; it < 11; ++it) {
            int i4 = tid + it * 256;
            if (i4 < 2805) { float4 v = xb4[i4]; xv0[it] = pk2(v.x, v.y); xv1[it] = pk2(v.z, v.w); }
        }
    };
    auto stagex = [&]() {
        #pragma unroll
        for (int it = 0; it < 11; ++it) {
            int i4 = tid + it * 256;
            if (i4 < 2805) {
                int fc  = i4 * 4;
                int row = (int)(((unsigned long long)fc * 41121ull) >> 22);  // /102
                int e   = fc - row * EMB;
                int tile = row >= HALFS;
                int lr   = row - HALFS * tile;
                int ba   = tile * XTILE + lr * XS + e;
                if (e == 100) {
                    int rowb  = row + 1;
                    int tileb = rowb >= HALFS;
                    int lrb   = rowb - HALFS * tileb;
                    *(unsigned*)(u + ba) = xv0[it];
                    *(unsigned*)(u + tileb * XTILE + lrb * XS) = xv1[it];
                } else {
                    uint2 t2; t2.x = xv0[it]; t2.y = xv1[it];
                    *(uint2*)(u + ba) = t2;
                }
            }
        }
    };

    loadx(blockIdx.x);
    const int stride = (int)gridDim.x;

    bf16x8 ax[4][4];
    bf16x8 zz = {};

    #pragma unroll 1
    for (int p = blockIdx.x; p < B; p += stride) {
        stagex();
        __syncthreads();                 // bar1: x staged

        // G A-frags (transient live range)
        bf16x8 am[2][4];
        #pragma unroll
        for (int mi2 = 0; mi2 < 2; ++mi2) {
            const int mt = w + 4 * mi2;
            #pragma unroll
            for (int kk = 0; kk < 4; ++kk)
                am[mi2][kk] = (mt < 7) ? *(const bf16x8*)(Mt + (16 * mt + r) * MTS + 32 * kk + 8 * g) : zz;
        }

        // y0 = x0 @ G -> slotC
        #pragma unroll
        for (int stl = 0; stl < 4; ++stl) {
            const short* xb = slotA + (16 * stl + r) * XS;
            bf16x8 bx[4];
            #pragma unroll
            for (int kk = 0; kk < 3; ++kk) bx[kk] = *(const bf16x8*)(xb + 32 * kk + 8 * g);
            bx[3] = zz;
            if (g == 0) bx[3] = *(const bf16x8*)(xb + 96);
            #pragma unroll
            for (int mi2 = 0; mi2 < 2; ++mi2) {
                const int mt = w + 4 * mi2;
                if (mt < 7) {
                    f32x4 acc = {0.f, 0.f, 0.f, 0.f};
                    #pragma unroll
                    for (int kk = 0; kk < 4; ++kk)
                        acc = __builtin_amdgcn_mfma_f32_16x16x32_bf16(am[mi2][kk], bx[kk], acc, 0, 0, 0);
                    if (mt < 6 || g < 2) {
                        uint2 t2; t2.x = pk2(acc[0], acc[1]); t2.y = pk2(acc[2], acc[3]);
                        *(uint2*)(slotC + (16 * stl + r) * XS + 16 * mt + 4 * g) = t2;
                    }
                }
            }
        }
        __syncthreads();                 // bar2: y0 visible

        // hoist ax = x1 (slotB)
        #pragma unroll
        for (int mt = 0; mt < 4; ++mt) {
            const short* xb = slotB + (16 * mt + r) * XS;
            #pragma unroll
            for (int kk = 0; kk < 3; ++kk) ax[mt][kk] = *(const bf16x8*)(xb + 32 * kk + 8 * g);
            ax[mt][3] = zz;
            if (g == 0) ax[mt][3] = *(const bf16x8*)(xb + 96);
        }
        __syncthreads();                 // bar2b: hoists done -> slotB writable

        // y1 = x1 @ G (B = ax regs) -> slotB
        #pragma unroll
        for (int stl = 0; stl < 4; ++stl) {
            #pragma unroll
            for (int mi2 = 0; mi2 < 2; ++mi2) {
                const int mt = w + 4 * mi2;
                if (mt < 7) {
                    f32x4 acc = {0.f, 0.f, 0.f, 0.f};
                    #pragma unroll
                    for (int kk = 0; kk < 4; ++kk)
                        acc = __builtin_amdgcn_mfma_f32_16x16x32_bf16(am[mi2][kk], ax[stl][kk], acc, 0, 0, 0);
                    if (mt < 6 || g < 2) {
                        uint2 t2; t2.x = pk2(acc[0], acc[1]); t2.y = pk2(acc[2], acc[3]);
                        *(uint2*)(slotB + (16 * stl + r) * XS + 16 * mt + 4 * g) = t2;
                    }
                }
            }
        }

        if (p + stride < B) loadx(p + stride);   // prefetch spans both halves

        const int src0 = ((g & 1) << 5) + r;
        const int src1 = src0 + 16;
        const bool hi  = (g >> 1) != 0;

        // ---- halves: ROLLED loop, body emitted once ----
        #pragma unroll 1
        for (int half = 0; half < 2; ++half) {
            if (half == 1) {
                __syncthreads();         // bar3: y1 visible; slotC reads done
                #pragma unroll
                for (int mt = 0; mt < 4; ++mt) {
                    const short* xb = slotA + (16 * mt + r) * XS;
                    #pragma unroll
                    for (int kk = 0; kk < 3; ++kk) ax[mt][kk] = *(const bf16x8*)(xb + 32 * kk + 8 * g);
                    ax[mt][3] = zz;
                    if (g == 0) ax[mt][3] = *(const bf16x8*)(xb + 96);
                }
            }
            const short* yo = half ? slotB : slotC;

            // v-GEMM (A = ax, B = wvf; regs only)
            unsigned vpk[4][3][2];
            #pragma unroll
            for (int st = 0; st < 4; ++st) {
                #pragma unroll
                for (int mi = 0; mi < 3; ++mi) {
                    f32x4 acc = {0.f, 0.f, 0.f, 0.f};
                    #pragma unroll
                    for (int kk = 0; kk < 4; ++kk)
                        acc = __builtin_amdgcn_mfma_f32_16x16x32_bf16(ax[st][kk], wvf[mi][kk], acc, 0, 0, 0);
                    vpk[st][mi][0] = pk2(acc[0], acc[1]);
                    vpk[st][mi][1] = pk2(acc[2], acc[3]);
                }
            }

            // v-exchange -> va[3][2] (static indices)
            bf16x8 va[3][2];
            #pragma unroll
            for (int mi = 0; mi < 3; ++mi) {
                unsigned e00 = (unsigned)__shfl((int)vpk[0][mi][0], src0), e01 = (unsigned)__shfl((int)vpk[0][mi][1], src0);
                unsigned e02 = (unsigned)__shfl((int)vpk[0][mi][0], src1), e03 = (unsigned)__shfl((int)vpk[0][mi][1], src1);
                unsigned f00 = (unsigned)__shfl((int)vpk[1][mi][0], src0), f01 = (unsigned)__shfl((int)vpk[1][mi][1], src0);
                unsigned f02 = (unsigned)__shfl((int)vpk[1][mi][0], src1), f03 = (unsigned)__shfl((int)vpk[1][mi][1], src1);
                uint4 u0;
                u0.x = hi ? f00 : e00; u0.y = hi ? f01 : e01; u0.z = hi ? f02 : e02; u0.w = hi ? f03 : e03;
                unsigned e10 = (unsigned)__shfl((int)vpk[2][mi][0], src0), e11 = (unsigned)__shfl((int)vpk[2][mi][1], src0);
                unsigned e12 = (unsigned)__shfl((int)vpk[2][mi][0], src1), e13 = (unsigned)__shfl((int)vpk[2][mi][1], src1);
                unsigned f10 = (unsigned)__shfl((int)vpk[3][mi][0], src0), f11 = (unsigned)__shfl((int)vpk[3][mi][1], src0);
                unsigned f12 = (unsigned)__shfl((int)vpk[3][mi][0], src1), f13 = (unsigned)__shfl((int)vpk[3][mi][1], src1);
                uint4 u1;
                u1.x = hi ? f10 : e10; u1.y = hi ? f11 : e11; u1.z = hi ? f12 : e12; u1.w = hi ? f13 : e13;
                __builtin_memcpy(&va[mi][0], &u0, 16);
                __builtin_memcpy(&va[mi][1], &u1, 16);
            }

            const size_t obase = (size_t)p * (SEQ * HEAD) + (size_t)(half * HALFS) * HEAD;

            // ---- c-loop: ROLLED; scores+softmax+exchange+PV+store per iteration ----
            #pragma unroll 1
            for (int c = 0; c < 4; ++c) {
                const short* yb = yo + (16 * c + r) * XS;
                bf16x8 by[4];
                #pragma unroll
                for (int kk = 0; kk < 3; ++kk) by[kk] = *(const bf16x8*)(yb + 32 * kk + 8 * g);
                by[3] = zz;
                if (g == 0) by[3] = *(const bf16x8*)(yb + 96);

                float sc[4][4];
                #pragma unroll
                for (int mt = 0; mt < 4; ++mt) {
                    f32x4 acc = {0.f, 0.f, 0.f, 0.f};
                    #pragma unroll
                    for (int kk = 0; kk < 4; ++kk)
                        acc = __builtin_amdgcn_mfma_f32_16x16x32_bf16(ax[mt][kk], by[kk], acc, 0, 0, 0);
                    #pragma unroll
                    for (int j = 0; j < 4; ++j) sc[mt][j] = acc[j];
                }
                #pragma unroll
                for (int j = 0; j < 4; ++j)
                    if (48 + 4 * g + j >= HALFS) sc[3][j] = -1e30f;

                float mx = -1e30f;
                #pragma unroll
                for (int mt = 0; mt < 4; ++mt) {
                    #pragma unroll
                    for (int j = 0; j < 4; ++j) mx = fmaxf(mx, sc[mt][j]);
                }
                mx = fmaxf(mx, __shfl_xor(mx, 16));
                mx = fmaxf(mx, __shfl_xor(mx, 32));
                float pr[4][4];
                float sum = 0.f;
                #pragma unroll
                for (int mt = 0; mt < 4; ++mt) {
                    #pragma unroll
                    for (int j = 0; j < 4; ++j) { pr[mt][j] = __expf(sc[mt][j] - mx); sum += pr[mt][j]; }
                }
                sum += __shfl_xor(sum, 16);
                sum += __shfl_xor(sum, 32);
                float rs = 1.0f / sum;

                unsigned pu[4][2];
                #pragma unroll
                for (int mt = 0; mt < 4; ++mt) {
                    pu[mt][0] = pk2(pr[mt][0] * rs, pr[mt][1] * rs);
                    pu[mt][1] = pk2(pr[mt][2] * rs, pr[mt][3] * rs);
                }
                unsigned A00 = (unsigned)__shfl((int)pu[0][0], src0), A01 = (unsigned)__shfl((int)pu[0][1], src0);
                unsigned A02 = (unsigned)__shfl((int)pu[0][0], src1), A03 = (unsigned)__shfl((int)pu[0][1], src1);
                unsigned B00 = (unsigned)__shfl((int)pu[1][0], src0), B01 = (unsigned)__shfl((int)pu[1][1], src0);
                unsigned B02 = (unsigned)__shfl((int)pu[1][0], src1), B03 = (unsigned)__shfl((int)pu[1][1], src1);
                unsigned C00 = (unsigned)__shfl((int)pu[2][0], src0), C01 = (unsigned)__shfl((int)pu[2][1], src0);
                unsigned C02 = (unsigned)__shfl((int)pu[2][0], src1), C03 = (unsigned)__shfl((int)pu[2][1], src1);
                unsigned D00 = (unsigned)__shfl((int)pu[3][0], src0), D01 = (unsigned)__shfl((int)pu[3][1], src0);
                unsigned D02 = (unsigned)__shfl((int)pu[3][0], src1), D03 = (unsigned)__shfl((int)pu[3][1], src1);
                uint4 q0, q1;
                q0.x = hi ? B00 : A00; q0.y = hi ? B01 : A01; q0.z = hi ? B02 : A02; q0.w = hi ? B03 : A03;
                q1.x = hi ? D00 : C00; q1.y = hi ? D01 : C01; q1.z = hi ? D02 : C02; q1.w = hi ? D03 : C03;
                bf16x8 bp0, bp1;
                __builtin_memcpy(&bp0, &q0, 16);
                __builtin_memcpy(&bp1, &q1, 16);

                const int srow  = 16 * c + r;
                const bool valid = srow < HALFS;
                float* orow = out + obase + (size_t)srow * HEAD;
                #pragma unroll
                for (int mi = 0; mi < 3; ++mi) {
                    f32x4 acc = {0.f, 0.f, 0.f, 0.f};
                    acc = __builtin_amdgcn_mfma_f32_16x16x32_bf16(va[mi][0], bp0, acc, 0, 0, 0);
                    acc = __builtin_amdgcn_mfma_f32_16x16x32_bf16(va[mi][1], bp1, acc, 0, 0, 0);
                    if (valid) {
                        float4 st4; st4.x = acc[0]; st4.y = acc[1]; st4.z = acc[2]; st4.w = acc[3];
                        *(float4*)(orow + 16 * (w + 4 * mi) + 4 * g) = st4;
                    }
                }
            }
        }
        __syncthreads();                 // bar4: slotA/slotB reads done before next stage
    }
}

extern "C" void kernel_launch(void* const* d_in, const int* in_sizes, int n_in,
                              void* d_out, int out_size, void* d_ws, size_t ws_size,
                              hipStream_t stream) {
    const float* x  = (const float*)d_in[0];
    const float* Wq = (const float*)d_in[1];
    const float* Wk = (const float*)d_in[2];
    const float* Wv = (const float*)d_in[3];
    short* ws = (short*)d_ws;                       // needs (14336+24576)*2 = 77824 B
    int B = in_sizes[0] / (SEQ * EMB);              // 8192
    int prep_elems = MT_SHORTS + HEAD * WES;
    prep<<<(prep_elems + 255) / 256, 256, 0, stream>>>(Wq, Wk, Wv, ws);
    attn_head<<<512, 256, 0, stream>>>(x, ws, (float*)d_out, B);
}

// Round 11
// 336.341 us; speedup vs baseline: 1.2098x; 1.0525x over previous
//
#include <hip/hip_runtime.h>
#include <hip/hip_bf16.h>

#define SEQ   110
#define HALFS 55
#define EMB   102
#define HEAD  192

typedef short bf16x8 __attribute__((ext_vector_type(8)));
typedef float f32x4  __attribute__((ext_vector_type(4)));

#define XS    104               // tile row stride (shorts), 13 granules (odd)
#define XTILE (64 * XS)         // 6656 shorts per tile
#define PS    72                // P_lds row stride (shorts), 9 granules (odd)
#define MTS   128               // Mt row stride (shorts)
#define MTROWS 112
#define MT_SHORTS (MTROWS * MTS)   // 14336
#define WES   128               // WvT e-stride

__device__ __forceinline__ short f2bf(float f) {
    unsigned u = __float_as_uint(f);
    unsigned r = u + 0x7fffu + ((u >> 16) & 1u);   // RNE
    return (short)(r >> 16);
}
__device__ __forceinline__ unsigned pk2(float a, float b) {
    return ((unsigned)(unsigned short)f2bf(b) << 16) | (unsigned short)f2bf(a);
}

// ws layout: [ Mt : 112x128 bf16 ][ WvT : 192x128 bf16 ]
// Mt[i][j] = scale * sum_h Wq[j][h] * Wk[i][h]; WvT[h][e] = Wv[e][h]; zero-padded.
__global__ void prep(const float* __restrict__ Wq, const float* __restrict__ Wk,
                     const float* __restrict__ Wv, short* __restrict__ ws) {
    int flat = blockIdx.x * 256 + threadIdx.x;
    if (flat < MT_SHORTS) {
        int i = flat >> 7, j = flat & 127;
        float v = 0.0f;
        if (i < EMB && j < EMB) {
            const float4* q4 = (const float4*)(Wq + j * HEAD);
            const float4* k4 = (const float4*)(Wk + i * HEAD);
            float s = 0.0f;
            #pragma unroll 4
            for (int h4 = 0; h4 < HEAD / 4; ++h4) {
                float4 a = q4[h4], b = k4[h4];
                s += a.x * b.x + a.y * b.y + a.z * b.z + a.w * b.w;
            }
            v = s * 0.07216878364870322f;   // 1/sqrt(192)
        }
        ws[flat] = f2bf(v);
    } else if (flat < MT_SHORTS + HEAD * WES) {
        int idx = flat - MT_SHORTS;
        int h = idx >> 7, e = idx & 127;
        float v = (e < EMB) ? Wv[e * HEAD + h] : 0.0f;
        ws[flat] = f2bf(v);
    }
}

// 512 persistent blocks (balanced), LDS 49.2KB, rolled loops (I$-small).
// DEDUP: wave w computes scores+softmax ONLY for its query tile c=w (was 4x
// redundant across waves), P goes through a 9KB LDS buffer in PV B-frag layout.
__global__ __launch_bounds__(256, 2)
void attn_head(const float* __restrict__ x, const short* __restrict__ ws,
               float* __restrict__ out, int B) {
    const int tid  = threadIdx.x;
    const int w    = tid >> 6;
    const int lane = tid & 63;
    const int g    = lane >> 4;
    const int r    = lane & 15;

    __shared__ __attribute__((aligned(16))) short u[3 * XTILE];   // 39936 B
    __shared__ __attribute__((aligned(16))) short P_lds[64 * PS]; // 9216 B
    short* slotA = u;                 // x half0
    short* slotB = u + XTILE;         // x half1 -> y half1
    short* slotC = u + 2 * XTILE;     // y half0

    const short* Mt  = ws;
    const short* WvT = ws + MT_SHORTS;

    bf16x8 wvf[3][4];
    #pragma unroll
    for (int mi = 0; mi < 3; ++mi) {
        const int hrow = 16 * (w + 4 * mi) + r;
        #pragma unroll
        for (int kk = 0; kk < 4; ++kk)
            wvf[mi][kk] = *(const bf16x8*)(WvT + hrow * WES + 32 * kk + 8 * g);
    }

    // one-time pad zeroing of slotA/slotB
    {
        unsigned long long* z = (unsigned long long*)u;
        #pragma unroll
        for (int i0 = 0; i0 < 2; ++i0) {
            int ii = tid + i0 * 256;
            if (ii < 468) z[(ii < 234 ? 1430 : 2860) + ii] = 0ull;
        }
        if (tid < 110)
            *(unsigned*)(u + (tid & 1) * XTILE + (tid >> 1) * XS + 102) = 0u;
    }

    unsigned xv0[11], xv1[11];
    auto loadx = [&](int batch) {
        const float4* xb4 = (const float4*)(x + (size_t)batch * (SEQ * EMB));
        #pragma unroll
        for (int it = 0; it < 11; ++it) {
            int i4 = tid + it * 256;
            if (i4 < 2805) { float4 v = xb4[i4]; xv0[it] = pk2(v.x, v.y); xv1[it] = pk2(v.z, v.w); }
        }
    };
    auto stagex = [&]() {
        #pragma unroll
        for (int it = 0; it < 11; ++it) {
            int i4 = tid + it * 256;
            if (i4 < 2805) {
                int fc  = i4 * 4;
                int row = (int)(((unsigned long long)fc * 41121ull) >> 22);  // /102
                int e   = fc - row * EMB;
                int tile = row >= HALFS;
                int lr   = row - HALFS * tile;
                int ba   = tile * XTILE + lr * XS + e;
                if (e == 100) {
                    int rowb  = row + 1;
                    int tileb = rowb >= HALFS;
                    int lrb   = rowb - HALFS * tileb;
                    *(unsigned*)(u + ba) = xv0[it];
                    *(unsigned*)(u + tileb * XTILE + lrb * XS) = xv1[it];
                } else {
                    uint2 t2; t2.x = xv0[it]; t2.y = xv1[it];
                    *(uint2*)(u + ba) = t2;
                }
            }
        }
    };

    loadx(blockIdx.x);
    const int stride = (int)gridDim.x;

    bf16x8 ax[4][4];
    bf16x8 zz = {};

    #pragma unroll 1
    for (int p = blockIdx.x; p < B; p += stride) {
        stagex();
        __syncthreads();                 // bar1: x staged

        // G A-frags (transient live range)
        bf16x8 am[2][4];
        #pragma unroll
        for (int mi2 = 0; mi2 < 2; ++mi2) {
            const int mt = w + 4 * mi2;
            #pragma unroll
            for (int kk = 0; kk < 4; ++kk)
                am[mi2][kk] = (mt < 7) ? *(const bf16x8*)(Mt + (16 * mt + r) * MTS + 32 * kk + 8 * g) : zz;
        }

        // y0 = x0 @ G -> slotC
        #pragma unroll
        for (int stl = 0; stl < 4; ++stl) {
            const short* xb = slotA + (16 * stl + r) * XS;
            bf16x8 bx[4];
            #pragma unroll
            for (int kk = 0; kk < 3; ++kk) bx[kk] = *(const bf16x8*)(xb + 32 * kk + 8 * g);
            bx[3] = zz;
            if (g == 0) bx[3] = *(const bf16x8*)(xb + 96);
            #pragma unroll
            for (int mi2 = 0; mi2 < 2; ++mi2) {
                const int mt = w + 4 * mi2;
                if (mt < 7) {
                    f32x4 acc = {0.f, 0.f, 0.f, 0.f};
                    #pragma unroll
                    for (int kk = 0; kk < 4; ++kk)
                        acc = __builtin_amdgcn_mfma_f32_16x16x32_bf16(am[mi2][kk], bx[kk], acc, 0, 0, 0);
                    if (mt < 6 || g < 2) {
                        uint2 t2; t2.x = pk2(acc[0], acc[1]); t2.y = pk2(acc[2], acc[3]);
                        *(uint2*)(slotC + (16 * stl + r) * XS + 16 * mt + 4 * g) = t2;
                    }
                }
            }
        }
        __syncthreads();                 // bar2: y0 visible

        // hoist ax = x1 (slotB)
        #pragma unroll
        for (int mt = 0; mt < 4; ++mt) {
            const short* xb = slotB + (16 * mt + r) * XS;
            #pragma unroll
            for (int kk = 0; kk < 3; ++kk) ax[mt][kk] = *(const bf16x8*)(xb + 32 * kk + 8 * g);
            ax[mt][3] = zz;
            if (g == 0) ax[mt][3] = *(const bf16x8*)(xb + 96);
        }
        __syncthreads();                 // bar2b: hoists done -> slotB writable

        // y1 = x1 @ G (B = ax regs) -> slotB
        #pragma unroll
        for (int stl = 0; stl < 4; ++stl) {
            #pragma unroll
            for (int mi2 = 0; mi2 < 2; ++mi2) {
                const int mt = w + 4 * mi2;
                if (mt < 7) {
                    f32x4 acc = {0.f, 0.f, 0.f, 0.f};
                    #pragma unroll
                    for (int kk = 0; kk < 4; ++kk)
                        acc = __builtin_amdgcn_mfma_f32_16x16x32_bf16(am[mi2][kk], ax[stl][kk], acc, 0, 0, 0);
                    if (mt < 6 || g < 2) {
                        uint2 t2; t2.x = pk2(acc[0], acc[1]); t2.y = pk2(acc[2], acc[3]);
                        *(uint2*)(slotB + (16 * stl + r) * XS + 16 * mt + 4 * g) = t2;
                    }
                }
            }
        }

        if (p + stride < B) loadx(p + stride);   // prefetch spans both halves

        const int src0 = ((g & 1) << 5) + r;
        const int src1 = src0 + 16;
        const bool hi  = (g >> 1) != 0;

        // ---- halves: rolled loop ----
        #pragma unroll 1
        for (int half = 0; half < 2; ++half) {
            if (half == 1) {
                __syncthreads();         // bar3: y1 visible; slotC + P_lds(half0) reads done
                #pragma unroll
                for (int mt = 0; mt < 4; ++mt) {
                    const short* xb = slotA + (16 * mt + r) * XS;
                    #pragma unroll
                    for (int kk = 0; kk < 3; ++kk) ax[mt][kk] = *(const bf16x8*)(xb + 32 * kk + 8 * g);
                    ax[mt][3] = zz;
                    if (g == 0) ax[mt][3] = *(const bf16x8*)(xb + 96);
                }
            }
            const short* yo = half ? slotB : slotC;

            // v-GEMM (A = ax, B = wvf; regs only)
            unsigned vpk[4][3][2];
            #pragma unroll
            for (int st = 0; st < 4; ++st) {
                #pragma unroll
                for (int mi = 0; mi < 3; ++mi) {
                    f32x4 acc = {0.f, 0.f, 0.f, 0.f};
                    #pragma unroll
                    for (int kk = 0; kk < 4; ++kk)
                        acc = __builtin_amdgcn_mfma_f32_16x16x32_bf16(ax[st][kk], wvf[mi][kk], acc, 0, 0, 0);
                    vpk[st][mi][0] = pk2(acc[0], acc[1]);
                    vpk[st][mi][1] = pk2(acc[2], acc[3]);
                }
            }

            // v-exchange -> va[3][2]
            bf16x8 va[3][2];
            #pragma unroll
            for (int mi = 0; mi < 3; ++mi) {
                unsigned e00 = (unsigned)__shfl((int)vpk[0][mi][0], src0), e01 = (unsigned)__shfl((int)vpk[0][mi][1], src0);
                unsigned e02 = (unsigned)__shfl((int)vpk[0][mi][0], src1), e03 = (unsigned)__shfl((int)vpk[0][mi][1], src1);
                unsigned f00 = (unsigned)__shfl((int)vpk[1][mi][0], src0), f01 = (unsigned)__shfl((int)vpk[1][mi][1], src0);
                unsigned f02 = (unsigned)__shfl((int)vpk[1][mi][0], src1), f03 = (unsigned)__shfl((int)vpk[1][mi][1], src1);
                uint4 u0;
                u0.x = hi ? f00 : e00; u0.y = hi ? f01 : e01; u0.z = hi ? f02 : e02; u0.w = hi ? f03 : e03;
                unsigned e10 = (unsigned)__shfl((int)vpk[2][mi][0], src0), e11 = (unsigned)__shfl((int)vpk[2][mi][1], src0);
                unsigned e12 = (unsigned)__shfl((int)vpk[2][mi][0], src1), e13 = (unsigned)__shfl((int)vpk[2][mi][1], src1);
                unsigned f10 = (unsigned)__shfl((int)vpk[3][mi][0], src0), f11 = (unsigned)__shfl((int)vpk[3][mi][1], src0);
                unsigned f12 = (unsigned)__shfl((int)vpk[3][mi][0], src1), f13 = (unsigned)__shfl((int)vpk[3][mi][1], src1);
                uint4 u1;
                u1.x = hi ? f10 : e10; u1.y = hi ? f11 : e11; u1.z = hi ? f12 : e12; u1.w = hi ? f13 : e13;
                __builtin_memcpy(&va[mi][0], &u0, 16);
                __builtin_memcpy(&va[mi][1], &u1, 16);
            }

            // ---- scores + softmax ONLY for this wave's query tile c = w ----
            {
                const short* yb = yo + (16 * w + r) * XS;
                bf16x8 by[4];
                #pragma unroll
                for (int kk = 0; kk < 3; ++kk) by[kk] = *(const bf16x8*)(yb + 32 * kk + 8 * g);
                by[3] = zz;
                if (g == 0) by[3] = *(const bf16x8*)(yb + 96);

                float sc[4][4];
                #pragma unroll
                for (int mt = 0; mt < 4; ++mt) {
                    f32x4 acc = {0.f, 0.f, 0.f, 0.f};
                    #pragma unroll
                    for (int kk = 0; kk < 4; ++kk)
                        acc = __builtin_amdgcn_mfma_f32_16x16x32_bf16(ax[mt][kk], by[kk], acc, 0, 0, 0);
                    #pragma unroll
                    for (int j = 0; j < 4; ++j) sc[mt][j] = acc[j];
                }
                #pragma unroll
                for (int j = 0; j < 4; ++j)
                    if (48 + 4 * g + j >= HALFS) sc[3][j] = -1e30f;

                float mx = -1e30f;
                #pragma unroll
                for (int mt = 0; mt < 4; ++mt) {
                    #pragma unroll
                    for (int j = 0; j < 4; ++j) mx = fmaxf(mx, sc[mt][j]);
                }
                mx = fmaxf(mx, __shfl_xor(mx, 16));
                mx = fmaxf(mx, __shfl_xor(mx, 32));
                float pr[4][4];
                float sum = 0.f;
                #pragma unroll
                for (int mt = 0; mt < 4; ++mt) {
                    #pragma unroll
                    for (int j = 0; j < 4; ++j) { pr[mt][j] = __expf(sc[mt][j] - mx); sum += pr[mt][j]; }
                }
                sum += __shfl_xor(sum, 16);
                sum += __shfl_xor(sum, 32);
                float rs = 1.0f / sum;

                // write P rows s = 16w+r (t = 16mt+4g..+3), packed bf16
                #pragma unroll
                for (int mt = 0; mt < 4; ++mt) {
                    uint2 t2;
                    t2.x = pk2(pr[mt][0] * rs, pr[mt][1] * rs);
                    t2.y = pk2(pr[mt][2] * rs, pr[mt][3] * rs);
                    *(uint2*)(P_lds + (16 * w + r) * PS + 16 * mt + 4 * g) = t2;
                }
            }
            __syncthreads();             // P-bar: all waves' P rows visible

            // ---- PV per c: bp frags read straight from P_lds ----
            const size_t obase = (size_t)p * (SEQ * HEAD) + (size_t)(half * HALFS) * HEAD;
            #pragma unroll
            for (int c = 0; c < 4; ++c) {
                const short* pb = P_lds + (16 * c + r) * PS + 8 * g;
                bf16x8 bp0 = *(const bf16x8*)(pb);
                bf16x8 bp1 = *(const bf16x8*)(pb + 32);
                const int srow  = 16 * c + r;
                const bool valid = srow < HALFS;
                float* orow = out + obase + (size_t)srow * HEAD;
                #pragma unroll
                for (int mi = 0; mi < 3; ++mi) {
                    f32x4 acc = {0.f, 0.f, 0.f, 0.f};
                    acc = __builtin_amdgcn_mfma_f32_16x16x32_bf16(va[mi][0], bp0, acc, 0, 0, 0);
                    acc = __builtin_amdgcn_mfma_f32_16x16x32_bf16(va[mi][1], bp1, acc, 0, 0, 0);
                    if (valid) {
                        float4 st4; st4.x = acc[0]; st4.y = acc[1]; st4.z = acc[2]; st4.w = acc[3];
                        *(float4*)(orow + 16 * (w + 4 * mi) + 4 * g) = st4;
                    }
                }
            }
        }
        __syncthreads();                 // bar4: slot/P reads done before next stage
    }
}

extern "C" void kernel_launch(void* const* d_in, const int* in_sizes, int n_in,
                              void* d_out, int out_size, void* d_ws, size_t ws_size,
                              hipStream_t stream) {
    const float* x  = (const float*)d_in[0];
    const float* Wq = (const float*)d_in[1];
    const float* Wk = (const float*)d_in[2];
    const float* Wv = (const float*)d_in[3];
    short* ws = (short*)d_ws;                       // needs (14336+24576)*2 = 77824 B
    int B = in_sizes[0] / (SEQ * EMB);              // 8192
    int prep_elems = MT_SHORTS + HEAD * WES;
    prep<<<(prep_elems + 255) / 256, 256, 0, stream>>>(Wq, Wk, Wv, ws);
    attn_head<<<512, 256, 0, stream>>>(x, ws, (float*)d_out, B);
}